// Round 4
// baseline (26.709 us; speedup 1.0000x reference)
//
#include <hip/hip_runtime.h>
#include <math.h>

#define BB 64
#define LL 131072
#define NF 8
#define FLEN 31

#define TPB 256
#define RPT 8
#define TILE (TPB * RPT)        // 2048 outputs per block
#define TCELLS (TILE / 4)       // 512 float4 cells per tile
#define NCELLS (TCELLS + 8)     // 520 staged cells (halo 4 each side)
#define ROWCELLS (LL / 4)       // 32768 cells per row

// XOR swizzle on float4-cell index (involution, within-64-cell groups):
// all wave patterns here are dense (c = base + lane) -> 8 lanes per 4-bank
// group = conflict-free for b128 reads and writes.
#define SWZ(c) ((c) ^ (((c) >> 3) & 7))

__global__ __launch_bounds__(TPB, 6) void adaptive_filter_fused(
    const float* __restrict__ x,
    const float* __restrict__ features,
    const float* __restrict__ fp,      // (NF, 1, FLEN)
    const float* __restrict__ W1,
    const float* __restrict__ b1,
    const float* __restrict__ W2,
    const float* __restrict__ b2,
    float* __restrict__ out)
{
    const int tiles_per_row = LL / TILE;            // 64
    const int row  = blockIdx.x / tiles_per_row;
    const int tile = blockIdx.x % tiles_per_row;
    const int tid  = threadIdx.x;

    __shared__ float4 lds4[NCELLS];                 // 8.3 KB
    __shared__ float cs[32];

    const float4* xrow4 = reinterpret_cast<const float4*>(x + (size_t)row * LL);
    const int cell_base = tile * TCELLS - 4;

    // ---- issue staging loads into regs early (zero-fill outside row) ----
    const int d0 = tid, d1 = tid + TPB, d2 = tid + 2 * TPB;
    const unsigned gc0 = (unsigned)(cell_base + d0);
    const unsigned gc1 = (unsigned)(cell_base + d1);
    const unsigned gc2 = (unsigned)(cell_base + d2);
    float4 v0 = make_float4(0.f, 0.f, 0.f, 0.f);
    float4 v1 = v0, v2 = v0;
    if (gc0 < ROWCELLS) v0 = xrow4[gc0];
    if (gc1 < ROWCELLS) v1 = xrow4[gc1];
    const bool has2 = (tid < NCELLS - 2 * TPB);     // 8 threads
    if (has2 && gc2 < ROWCELLS) v2 = xrow4[gc2];

    // ---- taps MLP on lanes < 31 (overlaps global-load latency) ----
    if (tid < FLEN) {
        const int t = tid;
        float f[NF];
        #pragma unroll
        for (int j = 0; j < NF; ++j) f[j] = features[row * NF + j];

        float h[NF];
        #pragma unroll
        for (int i = 0; i < NF; ++i) {
            float s = b1[i];
            #pragma unroll
            for (int j = 0; j < NF; ++j) s = fmaf(f[j], W1[i * NF + j], s);
            h[i] = fmaxf(s, 0.0f);
        }

        float w[NF];
        float m = -1e30f;
        #pragma unroll
        for (int i = 0; i < NF; ++i) {
            float s = b2[i];
            #pragma unroll
            for (int j = 0; j < NF; ++j) s = fmaf(h[j], W2[i * NF + j], s);
            w[i] = s;
            m = fmaxf(m, s);
        }
        float denom = 0.0f;
        #pragma unroll
        for (int i = 0; i < NF; ++i) { w[i] = expf(w[i] - m); denom += w[i]; }
        const float inv = 1.0f / denom;

        float s = 0.0f;
        #pragma unroll
        for (int ff = 0; ff < NF; ++ff) s = fmaf(w[ff] * inv, fp[ff * FLEN + t], s);
        cs[t] = s;
    }

    // ---- LDS staging writes (swizzled placement) ----
    lds4[SWZ(d0)] = v0;
    lds4[SWZ(d1)] = v1;
    if (has2) lds4[SWZ(d2)] = v2;

    __syncthreads();

    // ---- taps to SGPRs: one broadcast read + 31 readlane ----
    const float tv = cs[tid & 31];
    float tap[FLEN];
    #pragma unroll
    for (int t = 0; t < FLEN; ++t)
        tap[t] = __int_as_float(__builtin_amdgcn_readlane(__float_as_int(tv), t));

    // ---- output-interleaved groups: lane l of wave w owns cells 128w+64g+l ----
    const int wv = tid >> 6, ln = tid & 63;
    float4* orow4 = reinterpret_cast<float4*>(out + (size_t)row * LL) + tile * TCELLS;

    #pragma unroll
    for (int g = 0; g < 2; ++g) {
        const int cg = 128 * wv + 64 * g + ln;      // output cell within tile

        // window floats w[j] = x[row, tile*2048 + 4*cg - 16 + j], j = 0..35
        // lds cells cg .. cg+8 (dense per wave instruction)
        float win[36];
        #pragma unroll
        for (int k = 0; k < 9; ++k) {
            const float4 v = lds4[SWZ(cg + k)];
            win[4 * k + 0] = v.x; win[4 * k + 1] = v.y;
            win[4 * k + 2] = v.z; win[4 * k + 3] = v.w;
        }

        // out[4*cg + r] = sum_t tap[t] * win[r + 1 + t], r = 0..3
        float a0 = 0.f, a1 = 0.f, a2 = 0.f, a3 = 0.f;
        #pragma unroll
        for (int t = 0; t < FLEN; ++t) {
            a0 = fmaf(tap[t], win[t + 1], a0);
            a1 = fmaf(tap[t], win[t + 2], a1);
            a2 = fmaf(tap[t], win[t + 3], a2);
            a3 = fmaf(tap[t], win[t + 4], a3);
        }

        orow4[cg] = make_float4(a0, a1, a2, a3);    // dense: lane stride 16B
    }
}

extern "C" void kernel_launch(void* const* d_in, const int* in_sizes, int n_in,
                              void* d_out, int out_size, void* d_ws, size_t ws_size,
                              hipStream_t stream) {
    const float* x        = (const float*)d_in[0];
    const float* features = (const float*)d_in[1];
    const float* fp       = (const float*)d_in[2];
    const float* W1       = (const float*)d_in[3];
    const float* b1       = (const float*)d_in[4];
    const float* W2       = (const float*)d_in[5];
    const float* b2       = (const float*)d_in[6];
    float* out = (float*)d_out;

    const int grid = BB * (LL / TILE);  // 64 * 64 = 4096 blocks
    adaptive_filter_fused<<<grid, TPB, 0, stream>>>(x, features, fp, W1, b1, W2, b2, out);
}

// Round 6
// 19.038 us; speedup vs baseline: 1.4029x; 1.4029x over previous
//
#include <hip/hip_runtime.h>
#include <math.h>

#define BB 64
#define LL 131072
#define NF 8
#define FLEN 31

#define TPB 256
#define RPT 8
#define TILE (TPB * RPT)        // 2048 outputs per block
#define TCELLS (TILE / 4)       // 512 float4 cells per tile
#define NCELLS (TCELLS + 8)     // 520 staged cells (halo 4 each side)
#define ROWCELLS (LL / 4)       // 32768 cells per row

typedef float f32x4 __attribute__((ext_vector_type(4)));

// XOR swizzle on float4-cell index (involution, within-64-cell groups):
// dense writes (c = base+l) and strided reads (c = 2l+const) both spread
// uniformly: 8 lanes per 4-bank group = conflict-free for b128.
#define SWZ(c) ((c) ^ (((c) >> 3) & 7))

__global__ __launch_bounds__(TPB, 6) void adaptive_filter_fused(
    const float* __restrict__ x,
    const float* __restrict__ features,
    const float* __restrict__ fp,      // (NF, 1, FLEN)
    const float* __restrict__ W1,
    const float* __restrict__ b1,
    const float* __restrict__ W2,
    const float* __restrict__ b2,
    float* __restrict__ out)
{
    const int tiles_per_row = LL / TILE;            // 64
    const int row  = blockIdx.x / tiles_per_row;
    const int tile = blockIdx.x % tiles_per_row;
    const int tid  = threadIdx.x;

    __shared__ f32x4 lds4[NCELLS];                  // 8.3 KB
    __shared__ float cs[32];

    const f32x4* xrow4 = reinterpret_cast<const f32x4*>(x + (size_t)row * LL);
    const int cell_base = tile * TCELLS - 4;

    // ---- issue staging loads into regs early (zero-fill outside row) ----
    // non-temporal: x is streamed exactly once
    const int d0 = tid, d1 = tid + TPB, d2 = tid + 2 * TPB;
    const unsigned gc0 = (unsigned)(cell_base + d0);
    const unsigned gc1 = (unsigned)(cell_base + d1);
    const unsigned gc2 = (unsigned)(cell_base + d2);
    f32x4 v0 = (f32x4)(0.0f);
    f32x4 v1 = v0, v2 = v0;
    if (gc0 < ROWCELLS) v0 = __builtin_nontemporal_load(&xrow4[gc0]);
    if (gc1 < ROWCELLS) v1 = __builtin_nontemporal_load(&xrow4[gc1]);
    const bool has2 = (tid < NCELLS - 2 * TPB);     // 8 threads
    if (has2 && gc2 < ROWCELLS) v2 = __builtin_nontemporal_load(&xrow4[gc2]);

    // ---- taps MLP on lanes < 31 (overlaps global-load latency) ----
    if (tid < FLEN) {
        const int t = tid;
        float f[NF];
        #pragma unroll
        for (int j = 0; j < NF; ++j) f[j] = features[row * NF + j];

        float h[NF];
        #pragma unroll
        for (int i = 0; i < NF; ++i) {
            float s = b1[i];
            #pragma unroll
            for (int j = 0; j < NF; ++j) s = fmaf(f[j], W1[i * NF + j], s);
            h[i] = fmaxf(s, 0.0f);
        }

        float w[NF];
        float m = -1e30f;
        #pragma unroll
        for (int i = 0; i < NF; ++i) {
            float s = b2[i];
            #pragma unroll
            for (int j = 0; j < NF; ++j) s = fmaf(h[j], W2[i * NF + j], s);
            w[i] = s;
            m = fmaxf(m, s);
        }
        float denom = 0.0f;
        #pragma unroll
        for (int i = 0; i < NF; ++i) { w[i] = expf(w[i] - m); denom += w[i]; }
        const float inv = 1.0f / denom;

        float s = 0.0f;
        #pragma unroll
        for (int ff = 0; ff < NF; ++ff) s = fmaf(w[ff] * inv, fp[ff * FLEN + t], s);
        cs[t] = s;
    }

    // ---- LDS staging writes (swizzled placement) ----
    lds4[SWZ(d0)] = v0;
    lds4[SWZ(d1)] = v1;
    if (has2) lds4[SWZ(d2)] = v2;

    __syncthreads();

    // ---- taps to SGPRs: one broadcast read + 31 readlane ----
    const float tv = cs[tid & 31];
    float tap[FLEN];
    #pragma unroll
    for (int t = 0; t < FLEN; ++t)
        tap[t] = __int_as_float(__builtin_amdgcn_readlane(__float_as_int(tv), t));

    // ---- window: 10 swizzled b128 reads -> 40 floats, two halves ----
    // w[j] = x[row, tile*2048 + 8*tid - 16 + j],  j = 0..39
    float wA[20], wB[20];
    #pragma unroll
    for (int k = 0; k < 5; ++k) {
        const f32x4 v = lds4[SWZ(2 * tid + k)];
        wA[4 * k + 0] = v.x; wA[4 * k + 1] = v.y;
        wA[4 * k + 2] = v.z; wA[4 * k + 3] = v.w;
    }
    #pragma unroll
    for (int k = 0; k < 5; ++k) {
        const f32x4 v = lds4[SWZ(2 * tid + 5 + k)];
        wB[4 * k + 0] = v.x; wB[4 * k + 1] = v.y;
        wB[4 * k + 2] = v.z; wB[4 * k + 3] = v.w;
    }

    // out[8*tid + r] = sum_t tap[t] * w[r + 1 + t]
    float acc[RPT];
    #pragma unroll
    for (int r = 0; r < RPT; ++r) acc[r] = 0.0f;

    #pragma unroll
    for (int r = 0; r < RPT; ++r) {
        #pragma unroll
        for (int t = 0; t <= 18 - r; ++t)          // j = r+1+t <= 19
            acc[r] = fmaf(tap[t], wA[r + 1 + t], acc[r]);
        #pragma unroll
        for (int t = 19 - r; t < FLEN; ++t)        // j-20 = r+t-19 in [0, r+11]
            acc[r] = fmaf(tap[t], wB[r + t - 19], acc[r]);
    }

    // ---- direct stores: two float4 per thread (32B lane stride), non-temporal ----
    f32x4* orow4 = reinterpret_cast<f32x4*>(out + (size_t)row * LL) + tile * TCELLS;
    f32x4 s0; s0.x = acc[0]; s0.y = acc[1]; s0.z = acc[2]; s0.w = acc[3];
    f32x4 s1; s1.x = acc[4]; s1.y = acc[5]; s1.z = acc[6]; s1.w = acc[7];
    __builtin_nontemporal_store(s0, &orow4[2 * tid + 0]);
    __builtin_nontemporal_store(s1, &orow4[2 * tid + 1]);
}

extern "C" void kernel_launch(void* const* d_in, const int* in_sizes, int n_in,
                              void* d_out, int out_size, void* d_ws, size_t ws_size,
                              hipStream_t stream) {
    const float* x        = (const float*)d_in[0];
    const float* features = (const float*)d_in[1];
    const float* fp       = (const float*)d_in[2];
    const float* W1       = (const float*)d_in[3];
    const float* b1       = (const float*)d_in[4];
    const float* W2       = (const float*)d_in[5];
    const float* b2       = (const float*)d_in[6];
    float* out = (float*)d_out;

    const int grid = BB * (LL / TILE);  // 64 * 64 = 4096 blocks
    adaptive_filter_fused<<<grid, TPB, 0, stream>>>(x, features, fp, W1, b1, W2, b2, out);
}